// Round 1
// baseline (1457.154 us; speedup 1.0000x reference)
//
#include <hip/hip_runtime.h>
#include <hip/hip_bf16.h>

#define BB 16
#define LL 4096
#define DD 64

typedef __attribute__((ext_vector_type(8))) short bf16x8;
typedef __attribute__((ext_vector_type(4))) float f32x4;

// LDS row strides (in shorts). 72 = 64 + 8 pad: fragment ds_read_b128 from
// row*72 lands (row+quad)*4 bank starts -> exactly 8 dwords/bank, conflict-free.
#define KST 72
#define VST 72
#define PST 72

__device__ __forceinline__ short f2bf(float f) {
    unsigned u = __builtin_bit_cast(unsigned, f);
    u += 0x7FFFu + ((u >> 16) & 1u);   // RNE; inputs are finite
    return (short)(u >> 16);
}

__global__ void __launch_bounds__(256)
attn_fused(const float* __restrict__ Q, const float* __restrict__ Km,
           const float* __restrict__ Vm, const unsigned char* __restrict__ Mask,
           float* __restrict__ Out, float* __restrict__ Attn)
{
    __shared__ short sK[64 * KST];          // sK[key][dim]   bf16
    __shared__ short sV[64 * VST];          // sV[dim][key]   bf16 (transposed)
    __shared__ short sP[4][16 * PST];       // per-wave P tile [qrow][key]
    __shared__ unsigned char sPad[64];
    __shared__ int sAny;

    const int tid  = threadIdx.x;
    const int wave = tid >> 6, lane = tid & 63;
    const int l15  = lane & 15, quad = lane >> 4;
    const int b = blockIdx.y, qt = blockIdx.x;
    const int q0 = qt << 6;

    if (tid < 64) sPad[tid] = (Mask[b * LL + q0 + tid] != 0) ? 1 : 0;
    __syncthreads();
    if (wave == 0) {
        unsigned long long bm = __ballot(sPad[lane] != 0);
        if (lane == 0) sAny = (bm != 0ull) ? 1 : 0;
    }
    __syncthreads();
    const int kbCount = sAny ? (LL >> 6) : (qt + 1);

    // ---- zero-fill attn cols >= kbCount*64 for this block's 64 rows ----
    {
        const float4 z = make_float4(0.f, 0.f, 0.f, 0.f);
        const int cstart = kbCount << 6;
        for (int r = 0; r < 16; ++r) {
            const int rg = q0 + (wave << 4) + r;
            float* rp = Attn + ((size_t)(b * LL + rg) << 12);
            for (int c = cstart + (lane << 2); c < LL; c += 256)
                *(float4*)(rp + c) = z;
        }
    }

    // ---- Q fragments (A layout: m=lane&15, k=quad*8+j, two K-steps) ----
    bf16x8 aq[2];
    {
        const float* qp = Q + (((size_t)(b * LL + q0 + (wave << 4) + l15)) << 6) + (quad << 3);
        #pragma unroll
        for (int ks = 0; ks < 2; ++ks) {
            float4 f0 = *(const float4*)(qp + ks * 32);
            float4 f1 = *(const float4*)(qp + ks * 32 + 4);
            bf16x8 a;
            a[0] = f2bf(f0.x); a[1] = f2bf(f0.y); a[2] = f2bf(f0.z); a[3] = f2bf(f0.w);
            a[4] = f2bf(f1.x); a[5] = f2bf(f1.y); a[6] = f2bf(f1.z); a[7] = f2bf(f1.w);
            aq[ks] = a;
        }
    }

    const float scale = 1.0f / 8.000001f;   // 1/(TEMPERATURE+EPS)

    // C/D layout: row = quad*4 + reg, col = lane&15 (m89/m91 verified)
    int rowg[4]; int padr[4]; float* attnRow[4];
    #pragma unroll
    for (int r = 0; r < 4; ++r) {
        const int rl = (wave << 4) + quad * 4 + r;
        rowg[r] = q0 + rl;
        padr[r] = sPad[rl];
        attnRow[r] = Attn + ((size_t)(b * LL + rowg[r]) << 12);
    }

    // ================= pass 1: softmax denominators =================
    float lsum[4] = {0.f, 0.f, 0.f, 0.f};
    for (int kb = 0; kb < kbCount; ++kb) {
        __syncthreads();
        {
            const float* kp = Km + (((size_t)(b * LL + (kb << 6))) << 6);
            #pragma unroll
            for (int i = 0; i < 4; ++i) {
                const int f4 = i * 256 + tid;
                const int row = f4 >> 4, d4 = f4 & 15;
                float4 x = *(const float4*)(kp + (row << 6) + (d4 << 2));
                short4 s; s.x = f2bf(x.x); s.y = f2bf(x.y); s.z = f2bf(x.z); s.w = f2bf(x.w);
                *(short4*)&sK[row * KST + (d4 << 2)] = s;
            }
        }
        __syncthreads();
        #pragma unroll
        for (int sub = 0; sub < 4; ++sub) {
            f32x4 acc = {0.f, 0.f, 0.f, 0.f};
            #pragma unroll
            for (int ks = 0; ks < 2; ++ks) {
                bf16x8 bk = *(bf16x8*)&sK[(sub * 16 + l15) * KST + ks * 32 + (quad << 3)];
                acc = __builtin_amdgcn_mfma_f32_16x16x32_bf16(aq[ks], bk, acc, 0, 0, 0);
            }
            const int colg = (kb << 6) + sub * 16 + l15;
            #pragma unroll
            for (int r = 0; r < 4; ++r) {
                float e = padr[r] ? 1.0f
                        : ((colg <= rowg[r]) ? __expf(acc[r] * scale) : 0.0f);
                lsum[r] += e;
            }
        }
    }
    #pragma unroll
    for (int r = 0; r < 4; ++r) {    // reduce over the 16 lanes sharing this row group
        float v = lsum[r];
        v += __shfl_xor(v, 1); v += __shfl_xor(v, 2);
        v += __shfl_xor(v, 4); v += __shfl_xor(v, 8);
        lsum[r] = 1.0f / v;          // lsum becomes inv_l
    }

    // ================= pass 2: write p, accumulate O = P·V =================
    f32x4 oacc[4];
    #pragma unroll
    for (int i = 0; i < 4; ++i) oacc[i] = (f32x4){0.f, 0.f, 0.f, 0.f};

    for (int kb = 0; kb < kbCount; ++kb) {
        __syncthreads();
        {
            const float* kp = Km + (((size_t)(b * LL + (kb << 6))) << 6);
            #pragma unroll
            for (int i = 0; i < 4; ++i) {
                const int f4 = i * 256 + tid;
                const int row = f4 >> 4, d4 = f4 & 15;
                float4 x = *(const float4*)(kp + (row << 6) + (d4 << 2));
                short4 s; s.x = f2bf(x.x); s.y = f2bf(x.y); s.z = f2bf(x.z); s.w = f2bf(x.w);
                *(short4*)&sK[row * KST + (d4 << 2)] = s;
            }
            const float* vp = Vm + (((size_t)(b * LL + (kb << 6))) << 6);
            #pragma unroll
            for (int i = 0; i < 2; ++i) {
                const int task = i * 256 + tid;   // 0..511
                const int kp2 = task & 31;        // key pair
                const int vd  = task >> 5;        // dim quad 0..15
                const float* vr = vp + (kp2 << 7) + (vd << 2);
                float4 a0 = *(const float4*)(vr);
                float4 a1 = *(const float4*)(vr + 64);
                #pragma unroll
                for (int jj = 0; jj < 4; ++jj) {  // pack 2 keys/dword -> ~2-way banks
                    const float x0 = (&a0.x)[jj], x1 = (&a1.x)[jj];
                    unsigned dw = (unsigned)(unsigned short)f2bf(x0)
                                | ((unsigned)(unsigned short)f2bf(x1) << 16);
                    *(unsigned*)&sV[(vd * 4 + jj) * VST + (kp2 << 1)] = dw;
                }
            }
        }
        __syncthreads();
        #pragma unroll
        for (int sub = 0; sub < 4; ++sub) {
            f32x4 acc = {0.f, 0.f, 0.f, 0.f};
            #pragma unroll
            for (int ks = 0; ks < 2; ++ks) {
                bf16x8 bk = *(bf16x8*)&sK[(sub * 16 + l15) * KST + ks * 32 + (quad << 3)];
                acc = __builtin_amdgcn_mfma_f32_16x16x32_bf16(aq[ks], bk, acc, 0, 0, 0);
            }
            const int col  = sub * 16 + l15;
            const int colg = (kb << 6) + col;
            #pragma unroll
            for (int r = 0; r < 4; ++r) {
                float e = padr[r] ? 1.0f
                        : ((colg <= rowg[r]) ? __expf(acc[r] * scale) : 0.0f);
                float p = e * lsum[r];
                attnRow[r][colg] = p;
                sP[wave][(quad * 4 + r) * PST + col] = f2bf(p);
            }
        }
        __syncthreads();   // sP round-trip (C layout -> A layout), m120 pattern
        #pragma unroll
        for (int ks = 0; ks < 2; ++ks) {
            bf16x8 ap = *(bf16x8*)&sP[wave][l15 * PST + ks * 32 + (quad << 3)];
            #pragma unroll
            for (int dsub = 0; dsub < 4; ++dsub) {
                bf16x8 bv = *(bf16x8*)&sV[(dsub * 16 + l15) * VST + ks * 32 + (quad << 3)];
                oacc[dsub] = __builtin_amdgcn_mfma_f32_16x16x32_bf16(ap, bv, oacc[dsub], 0, 0, 0);
            }
        }
    }

    // O already normalized (p used inv_l)
    #pragma unroll
    for (int dsub = 0; dsub < 4; ++dsub) {
        #pragma unroll
        for (int r = 0; r < 4; ++r) {
            Out[(((size_t)(b * LL + rowg[r])) << 6) + dsub * 16 + l15] = oacc[dsub][r];
        }
    }
}

extern "C" void kernel_launch(void* const* d_in, const int* in_sizes, int n_in,
                              void* d_out, int out_size, void* d_ws, size_t ws_size,
                              hipStream_t stream) {
    const float* Q = (const float*)d_in[0];
    const float* K = (const float*)d_in[1];
    const float* V = (const float*)d_in[2];
    const unsigned char* M = (const unsigned char*)d_in[3];  // jax bool mask (all-false in test; 0-bytes either way)
    float* Out  = (float*)d_out;                             // [B,L,D]
    float* Attn = (float*)d_out + (size_t)BB * LL * DD;      // [B,L,L]
    dim3 grid(LL / 64, BB);
    attn_fused<<<grid, 256, 0, stream>>>(Q, K, V, M, Out, Attn);
}